// Round 2
// baseline (51.895 us; speedup 1.0000x reference)
//
#include <hip/hip_runtime.h>

// ChiSquareLoss: per-image RGB 256-bin histograms of two [B,3,512,512] f32
// tensors in [0,1], normalized, chi-square distance summed over 768 bins,
// mean over batch.
//
// Layout facts (hard-wired to reference shapes):
//   H*W = 262144 -> per image 3*H*W = 786432 elems = 196608 float4 (F4_PER_IMG)
//   channel of f4-index fi (within image) = fi >> 16   (65536 f4 per channel)
//   normalization sum is EXACTLY 786432 per image (every pixel hits one bin).
//
// R1: latency-bound fix — 8 outstanding float4 loads per thread (was 1, VGPR=8),
//     grid exactly 2048 = 8 blocks/CU (was 12 -> 8+4 tail).

#define NCH       3
#define BINS      256
#define CBINS     (NCH * BINS)            // 768
#define F4_PER_IMG 196608
#define BPI       32                      // blocks per (input, image)
#define F4_PER_BLOCK (F4_PER_IMG / BPI)   // 6144
#define THREADS   256
#define F4_PER_THREAD (F4_PER_BLOCK / THREADS) // 24
#define BATCH     8
#define NBATCH    (F4_PER_THREAD / BATCH) // 3

__global__ __launch_bounds__(THREADS)
void hist_kernel(const float* __restrict__ in0,
                 const float* __restrict__ in1,
                 unsigned int* __restrict__ ghist,   // [2][B][768]
                 int B) {
    const int bid   = blockIdx.x;
    const int input = bid / (B * BPI);
    const int rem   = bid - input * (B * BPI);
    const int img   = rem / BPI;
    const int slice = rem - img * BPI;

    const float4* __restrict__ src =
        (const float4*)(input ? in1 : in0) + (size_t)img * F4_PER_IMG;
    const int sbase = slice * F4_PER_BLOCK;
    const int tid = threadIdx.x;
    const int w = tid >> 6;

    // per-wave privatized 768-bin histograms: 4 waves x 768 x 4B = 12 KB
    __shared__ unsigned int lhist[4][CBINS];
    #pragma unroll
    for (int i = 0; i < (4 * CBINS) / THREADS; ++i)
        ((unsigned int*)lhist)[tid + i * THREADS] = 0u;
    __syncthreads();

    #pragma unroll
    for (int bat = 0; bat < NBATCH; ++bat) {
        float4 v[BATCH];
        int fi[BATCH];
        // issue all BATCH loads first -> 8 outstanding vmcnt, latency overlapped
        #pragma unroll
        for (int j = 0; j < BATCH; ++j) {
            fi[j] = sbase + (bat * BATCH + j) * THREADS + tid;
            v[j] = src[fi[j]];
        }
        #pragma unroll
        for (int j = 0; j < BATCH; ++j) {
            const int offs = (fi[j] >> 16) << 8;     // channel * 256
            unsigned int* __restrict__ h = &lhist[w][offs];
            // truncation == floor for non-negative; clamp handles v==1.0
            int b0 = (int)fminf(fmaxf(v[j].x * 255.0f, 0.0f), 255.0f);
            int b1 = (int)fminf(fmaxf(v[j].y * 255.0f, 0.0f), 255.0f);
            int b2 = (int)fminf(fmaxf(v[j].z * 255.0f, 0.0f), 255.0f);
            int b3 = (int)fminf(fmaxf(v[j].w * 255.0f, 0.0f), 255.0f);
            atomicAdd(&h[b0], 1u);
            atomicAdd(&h[b1], 1u);
            atomicAdd(&h[b2], 1u);
            atomicAdd(&h[b3], 1u);
        }
    }
    __syncthreads();

    // flush: 768 bins, 4 copies -> 3 bins/thread
    #pragma unroll
    for (int k = 0; k < CBINS / THREADS; ++k) {
        const int bin = tid + k * THREADS;
        unsigned int s = lhist[0][bin] + lhist[1][bin] + lhist[2][bin] + lhist[3][bin];
        atomicAdd(&ghist[((size_t)input * B + img) * CBINS + bin], s);
    }
}

__global__ __launch_bounds__(1024)
void chi_kernel(const unsigned int* __restrict__ ghist, float* __restrict__ out, int B) {
    const unsigned int* __restrict__ h1 = ghist;
    const unsigned int* __restrict__ h2 = ghist + (size_t)B * CBINS;
    const int total = B * CBINS;
    const float N = (float)(NCH * 512 * 512);   // 786432, exact per-image sum

    double acc = 0.0;
    for (int i = threadIdx.x; i < total; i += 1024) {
        float a1 = (float)h1[i] / N;
        float a2 = (float)h2[i] / N;
        float d = a1 - a2;
        float s = a1 + a2 + 1e-10f;
        acc += (double)(d * d / s);
    }

    // wave (64-lane) reduce
    #pragma unroll
    for (int off = 32; off > 0; off >>= 1)
        acc += __shfl_down(acc, off);

    __shared__ double wsum[16];
    if ((threadIdx.x & 63) == 0) wsum[threadIdx.x >> 6] = acc;
    __syncthreads();
    if (threadIdx.x == 0) {
        double t = 0.0;
        #pragma unroll
        for (int i = 0; i < 16; ++i) t += wsum[i];
        out[0] = (float)(t / (double)B);
    }
}

extern "C" void kernel_launch(void* const* d_in, const int* in_sizes, int n_in,
                              void* d_out, int out_size, void* d_ws, size_t ws_size,
                              hipStream_t stream) {
    const float* in0 = (const float*)d_in[0];
    const float* in1 = (const float*)d_in[1];
    const int B = in_sizes[0] / (NCH * 512 * 512);   // 32

    unsigned int* ghist = (unsigned int*)d_ws;
    const size_t hist_bytes = (size_t)2 * B * CBINS * sizeof(unsigned int);

    hipMemsetAsync(d_ws, 0, hist_bytes, stream);
    hist_kernel<<<2 * B * BPI, THREADS, 0, stream>>>(in0, in1, ghist, B);
    chi_kernel<<<1, 1024, 0, stream>>>(ghist, (float*)d_out, B);
}

// Round 3
// 51.663 us; speedup vs baseline: 1.0045x; 1.0045x over previous
//
#include <hip/hip_runtime.h>

// ChiSquareLoss: per-image RGB 256-bin histograms of two [B,3,512,512] f32
// tensors in [0,1], normalized, chi-square distance summed over 768 bins,
// mean over batch.
//
// R3 theory: LDS-atomic RMW serialization is the wall (~30 cy per wave-level
// ds_atomic with a single shared bin array). Fix: 16 lane-group sub-histograms
// interleaved [bin][sub] so lane (tid&15) owns sub-hist s at bank (s+16b)&31
// -> no same-address RMW serialization, ~2-way banks. 48 KB LDS, 3 blocks/CU,
// grid exactly 768. Block = exactly one channel -> scalar channel offset.

#define NCH       3
#define BINS      256
#define CBINS     (NCH * BINS)            // 768
#define NSUB      16
#define F4_PER_IMG 196608
#define BPI       12                      // blocks per (input, image); 16384 | 65536 -> 1 channel/block
#define F4_PER_BLOCK (F4_PER_IMG / BPI)   // 16384
#define THREADS   256
#define F4_PER_THREAD (F4_PER_BLOCK / THREADS) // 64
#define BATCH     4
#define NBATCH    (F4_PER_THREAD / BATCH) // 16 (even -> clean ping-pong)

__device__ __forceinline__ void proc4(const float4* v, unsigned int* hb) {
    #pragma unroll
    for (int j = 0; j < BATCH; ++j) {
        // truncation == floor for non-negative; med3-style clamp handles v==1.0
        int b0 = (int)fminf(fmaxf(v[j].x * 255.0f, 0.0f), 255.0f);
        int b1 = (int)fminf(fmaxf(v[j].y * 255.0f, 0.0f), 255.0f);
        int b2 = (int)fminf(fmaxf(v[j].z * 255.0f, 0.0f), 255.0f);
        int b3 = (int)fminf(fmaxf(v[j].w * 255.0f, 0.0f), 255.0f);
        atomicAdd(hb + (b0 << 4), 1u);
        atomicAdd(hb + (b1 << 4), 1u);
        atomicAdd(hb + (b2 << 4), 1u);
        atomicAdd(hb + (b3 << 4), 1u);
    }
}

__global__ __launch_bounds__(THREADS)
void hist_kernel(const float* __restrict__ in0,
                 const float* __restrict__ in1,
                 unsigned int* __restrict__ ghist,   // [2][B][768]
                 int B) {
    const int bid   = blockIdx.x;
    const int input = bid / (B * BPI);
    const int rem   = bid - input * (B * BPI);
    const int img   = rem / BPI;
    const int slice = rem - img * BPI;
    const int choffs = (slice >> 2) << 8;   // channel*256, block-uniform (scalar)

    const float4* __restrict__ src = (const float4*)(input ? in1 : in0)
        + (size_t)img * F4_PER_IMG + (size_t)slice * F4_PER_BLOCK;
    const int tid = threadIdx.x;
    const int s = tid & (NSUB - 1);

    // [bin][sub] interleave: word (bin*16 + s) -> bank (16*bin + s) & 31
    __shared__ __align__(16) unsigned int lh[CBINS * NSUB];   // 48 KB
    #pragma unroll
    for (int i = 0; i < (CBINS * NSUB / 4) / THREADS; ++i)
        ((uint4*)lh)[tid + i * THREADS] = uint4{0u, 0u, 0u, 0u};
    __syncthreads();

    unsigned int* hb = lh + choffs * NSUB + s;   // element addr = hb + bin*16

    float4 va[BATCH], vb[BATCH];
    #pragma unroll
    for (int j = 0; j < BATCH; ++j) va[j] = src[j * THREADS + tid];

    #pragma unroll
    for (int bp = 0; bp < NBATCH / 2; ++bp) {
        const int b0 = 2 * bp;
        // prefetch odd batch while processing even
        #pragma unroll
        for (int j = 0; j < BATCH; ++j)
            vb[j] = src[((b0 + 1) * BATCH + j) * THREADS + tid];
        __builtin_amdgcn_sched_barrier(0);
        proc4(va, hb);
        // prefetch next even batch while processing odd
        if (b0 + 2 < NBATCH) {
            #pragma unroll
            for (int j = 0; j < BATCH; ++j)
                va[j] = src[((b0 + 2) * BATCH + j) * THREADS + tid];
        }
        __builtin_amdgcn_sched_barrier(0);
        proc4(vb, hb);
    }
    __syncthreads();

    // flush: 768 bins, 16 sub-copies each; 3 bins per thread, b128 reads
    #pragma unroll
    for (int k = 0; k < CBINS / THREADS; ++k) {
        const int bin = tid + k * THREADS;
        const uint4* p = (const uint4*)(lh + bin * NSUB);
        uint4 a = p[0], b = p[1], c = p[2], d = p[3];
        unsigned int sum = a.x + a.y + a.z + a.w
                         + b.x + b.y + b.z + b.w
                         + c.x + c.y + c.z + c.w
                         + d.x + d.y + d.z + d.w;
        atomicAdd(&ghist[((size_t)input * B + img) * CBINS + bin], sum);
    }
}

__global__ __launch_bounds__(1024)
void chi_kernel(const unsigned int* __restrict__ ghist, float* __restrict__ out, int B) {
    const unsigned int* __restrict__ h1 = ghist;
    const unsigned int* __restrict__ h2 = ghist + (size_t)B * CBINS;
    const int total = B * CBINS;
    const float N = (float)(NCH * 512 * 512);   // 786432, exact per-image sum

    double acc = 0.0;
    for (int i = threadIdx.x; i < total; i += 1024) {
        float a1 = (float)h1[i] / N;
        float a2 = (float)h2[i] / N;
        float d = a1 - a2;
        float sm = a1 + a2 + 1e-10f;
        acc += (double)(d * d / sm);
    }

    #pragma unroll
    for (int off = 32; off > 0; off >>= 1)
        acc += __shfl_down(acc, off);

    __shared__ double wsum[16];
    if ((threadIdx.x & 63) == 0) wsum[threadIdx.x >> 6] = acc;
    __syncthreads();
    if (threadIdx.x == 0) {
        double t = 0.0;
        #pragma unroll
        for (int i = 0; i < 16; ++i) t += wsum[i];
        out[0] = (float)(t / (double)B);
    }
}

extern "C" void kernel_launch(void* const* d_in, const int* in_sizes, int n_in,
                              void* d_out, int out_size, void* d_ws, size_t ws_size,
                              hipStream_t stream) {
    const float* in0 = (const float*)d_in[0];
    const float* in1 = (const float*)d_in[1];
    const int B = in_sizes[0] / (NCH * 512 * 512);   // 32

    unsigned int* ghist = (unsigned int*)d_ws;
    const size_t hist_bytes = (size_t)2 * B * CBINS * sizeof(unsigned int);

    hipMemsetAsync(d_ws, 0, hist_bytes, stream);
    hist_kernel<<<2 * B * BPI, THREADS, 0, stream>>>(in0, in1, ghist, B);
    chi_kernel<<<1, 1024, 0, stream>>>(ghist, (float*)d_out, B);
}